// Round 3
// baseline (1138.839 us; speedup 1.0000x reference)
//
#include <hip/hip_runtime.h>
#include <hip/hip_fp16.h>
#include <stdint.h>

// Problem: B=4, S=2048, IN=4096, OUT=12288
// Device encodings (deduced from rounds 0-2 + harness contract):
//   x      : const float*  (fp16 values promoted to fp32)  [8192][4096]
//   w_q    : const int*    (int8 values in int32 storage)  [12288][4096]
//   w_scale: const float*  [12288]
//   bias   : const float*  (fp16 promoted to fp32)         [12288]
//   out    : float*        [8192][12288]  (ref output fp16 -> "else float*")
#define M_TOK 8192
#define K_IN  4096
#define N_OUT 12288

#define BM 128
#define BN 128
#define BK 64

typedef int v4i_t __attribute__((ext_vector_type(4)));

// async global->LDS, 16 bytes per lane. LDS dest = wave-uniform base + lane*16.
__device__ __forceinline__ void load_lds16(const void* g, void* l) {
    __builtin_amdgcn_global_load_lds(
        (const __attribute__((address_space(1))) unsigned int*)g,
        (__attribute__((address_space(3))) unsigned int*)l, 16, 0, 0);
}

// ---------------- pack w_q: int32 storage -> int8 ----------------
__global__ __launch_bounds__(256) void pack_w_kernel(
    const int* __restrict__ wsrc, uint32_t* __restrict__ wdst) {
    const size_t i = (size_t)blockIdx.x * 256 + threadIdx.x;
    const int4 v = ((const int4*)wsrc)[i];
    uint32_t p = (uint32_t)(uint8_t)(int8_t)v.x
               | ((uint32_t)(uint8_t)(int8_t)v.y << 8)
               | ((uint32_t)(uint8_t)(int8_t)v.z << 16)
               | ((uint32_t)(uint8_t)(int8_t)v.w << 24);
    wdst[i] = p;
}

// ---------------- per-token dynamic quantization (fp32 input) ----------------
// one 256-thread block per token row of 4096 fp32; 16 floats per thread.
__global__ __launch_bounds__(256) void quant_kernel(
    const float* __restrict__ x, int8_t* __restrict__ xq, float* __restrict__ xs) {
    const int token = blockIdx.x;
    const int tid = threadIdx.x;
    const float4* src = (const float4*)(x + (size_t)token * K_IN);

    float v[16];
#pragma unroll
    for (int c = 0; c < 4; ++c) {
        float4 p = src[tid * 4 + c];
        v[c * 4 + 0] = p.x; v[c * 4 + 1] = p.y;
        v[c * 4 + 2] = p.z; v[c * 4 + 3] = p.w;
    }

    float amax = 0.f;
#pragma unroll
    for (int i = 0; i < 16; ++i) amax = fmaxf(amax, fabsf(v[i]));
#pragma unroll
    for (int off = 32; off >= 1; off >>= 1)
        amax = fmaxf(amax, __shfl_xor(amax, off));

    __shared__ float wmax[4];
    const int wave = tid >> 6, lane = tid & 63;
    if (lane == 0) wmax[wave] = amax;
    __syncthreads();
    amax = fmaxf(fmaxf(wmax[0], wmax[1]), fmaxf(wmax[2], wmax[3]));

    const float scale = fmaxf(amax, 1e-6f) / 127.0f;  // exact div, matches np
    if (tid == 0) xs[token] = scale;

    int8_t q[16];
#pragma unroll
    for (int i = 0; i < 16; ++i) {
        float r = rintf(v[i] / scale);       // half-to-even, matches jnp.round
        r = fminf(fmaxf(r, -128.f), 127.f);
        q[i] = (int8_t)(int)r;
    }
    uint4 packed;
    uint32_t* pw = (uint32_t*)&packed;
#pragma unroll
    for (int w = 0; w < 4; ++w) {
        pw[w] = (uint32_t)(uint8_t)q[w * 4 + 0]
              | ((uint32_t)(uint8_t)q[w * 4 + 1] << 8)
              | ((uint32_t)(uint8_t)q[w * 4 + 2] << 16)
              | ((uint32_t)(uint8_t)q[w * 4 + 3] << 24);
    }
    ((uint4*)(xq + (size_t)token * K_IN))[tid] = packed;
}

// ---------------- int8 GEMM + fused dequant/bias, fp32 out ----------------
// 128x128 tile, BK=64, 4 waves each 64x64 via 4x4 mfma_i32_16x16x64_i8.
__global__ __launch_bounds__(256) void gemm_kernel(
    const int8_t* __restrict__ xq, const float* __restrict__ xs,
    const int8_t* __restrict__ wq, const float* __restrict__ wscale,
    const float* __restrict__ bias, float* __restrict__ out) {
    __shared__ int8_t As[BM * BK];  // 8 KiB, row-major [128][64]
    __shared__ int8_t Bs[BN * BK];  // 8 KiB

    const int tid = threadIdx.x;
    const int wave = tid >> 6, lane = tid & 63;
    const int m0 = blockIdx.y * BM, n0 = blockIdx.x * BN;
    const int wr = wave >> 1, wc = wave & 1;

    const int8_t* Ag = xq + (size_t)m0 * K_IN;
    const int8_t* Bg = wq + (size_t)n0 * K_IN;

    // staging: thread tid covers tile bytes [tid*16, +16) per 64-row half.
    // LDS dest = wave*1024 + lane*16 = tid*16 == rowS*64 + colS (verified identity)
    const int rowS = tid >> 2;
    const int colS = (tid & 3) * 16;
    const size_t gOff0 = (size_t)rowS * K_IN + colS;
    const size_t gOff1 = (size_t)(rowS + 64) * K_IN + colS;
    int8_t* ldsA0 = As + wave * 1024;
    int8_t* ldsA1 = As + 4096 + wave * 1024;
    int8_t* ldsB0 = Bs + wave * 1024;
    int8_t* ldsB1 = Bs + 4096 + wave * 1024;

    // fragment: A[m=lane&15][k=(lane>>4)*16 + j], j=0..15 contiguous; B same
    const int fr = lane & 15;
    const int fq = lane >> 4;
    const int aoff = (wr * 64 + fr) * BK + fq * 16;
    const int boff = (wc * 64 + fr) * BK + fq * 16;

    v4i_t acc[4][4] = {};

    for (int k0 = 0; k0 < K_IN; k0 += BK) {
        __syncthreads();
        load_lds16(Ag + gOff0 + k0, ldsA0);
        load_lds16(Ag + gOff1 + k0, ldsA1);
        load_lds16(Bg + gOff0 + k0, ldsB0);
        load_lds16(Bg + gOff1 + k0, ldsB1);
        __syncthreads();

        v4i_t af[4], bf[4];
#pragma unroll
        for (int i = 0; i < 4; ++i)
            af[i] = *(const v4i_t*)(As + aoff + i * 16 * BK);
#pragma unroll
        for (int j = 0; j < 4; ++j)
            bf[j] = *(const v4i_t*)(Bs + boff + j * 16 * BK);
#pragma unroll
        for (int i = 0; i < 4; ++i)
#pragma unroll
            for (int j = 0; j < 4; ++j)
                acc[i][j] = __builtin_amdgcn_mfma_i32_16x16x64_i8(af[i], bf[j], acc[i][j], 0, 0, 0);
    }

    // epilogue: C/D layout col=lane&15, row=(lane>>4)*4+reg (dtype-independent)
    const int col = lane & 15;
    const int rq = lane >> 4;
#pragma unroll
    for (int i = 0; i < 4; ++i) {
        const int mb = m0 + wr * 64 + i * 16 + rq * 4;
        float xsv[4];
#pragma unroll
        for (int r = 0; r < 4; ++r) xsv[r] = xs[mb + r];
#pragma unroll
        for (int j = 0; j < 4; ++j) {
            const int n = n0 + wc * 64 + j * 16 + col;
            const float ws = wscale[n];
            const float bv = bias[n];
#pragma unroll
            for (int r = 0; r < 4; ++r) {
                float o = (float)acc[i][j][r] * xsv[r] * ws + bv;
                // match ref's final .astype(float16)
                o = __half2float(__float2half(o));
                out[(size_t)(mb + r) * N_OUT + n] = o;
            }
        }
    }
}

extern "C" void kernel_launch(void* const* d_in, const int* in_sizes, int n_in,
                              void* d_out, int out_size, void* d_ws, size_t ws_size,
                              hipStream_t stream) {
    const float* x      = (const float*)d_in[0];
    const int*   wq32   = (const int*)d_in[1];
    const float* wscale = (const float*)d_in[2];
    const float* bias   = (const float*)d_in[3];
    float* out = (float*)d_out;

    int8_t* xq  = (int8_t*)d_ws;                                            // 32 MiB
    float*  xs  = (float*)((char*)d_ws + (size_t)M_TOK * K_IN);             // 32 KiB
    int8_t* wq8 = (int8_t*)((char*)d_ws + (size_t)M_TOK * K_IN + 65536);    // 48 MiB

    pack_w_kernel<<<((size_t)N_OUT * K_IN) / 4 / 256, 256, 0, stream>>>(
        wq32, (uint32_t*)wq8);

    quant_kernel<<<M_TOK, 256, 0, stream>>>(x, xq, xs);

    dim3 grid(N_OUT / BN, M_TOK / BM);   // 96 x 64
    gemm_kernel<<<grid, dim3(256), 0, stream>>>(xq, xs, wq8, wscale, bias, out);
}